// Round 2
// baseline (14155.060 us; speedup 1.0000x reference)
//
#include <hip/hip_runtime.h>
#include <hip/hip_bf16.h>
#include <stdint.h>

// Problem constants
#define NB 64      // batch
#define NT 128     // seq len
#define NE 512     // embed
#define NH 1024    // hidden
#define NV 32000   // vocab
#define NM (NB*NT) // 8192 flattened (t-major: m = t*64 + b)

// Kernel config
#define NWG 256    // one workgroup per CU; LDS use forces 1 wg/CU -> all resident
#define NTH 512    // 8 waves
#define SLICE 16   // gate rows per wg (4 hidden units x 4 gates), col = gate*4 + unit
#define KPAD 16    // bf16 elements of row padding in LDS (4-way bank spread)
#define RHH (NH + KPAD)   // 1040
#define RIH0 (NE + KPAD)  // 528

// ws byte offsets
#define WS_FLAGS   0u
#define WS_H0      1024u
#define WS_H1      (WS_H0 + 2u*NB*NH*2u)        // 263168
#define WS_CNT     (WS_H1 + 2u*NB*NH*2u)        // 525312
#define WS_ZERO_END (WS_CNT + 4u*NB*NV)         // 8717312 (memset region)
#define WS_XS0     WS_ZERO_END                  // gathered embeddings, bf16 [NM][NE]
#define WS_XP      (WS_XS0 + 2u*NM*NE)          // 17105920, xproj0 sliced bf16 [NWG][NM][SLICE]
#define WS_NEEDED  (WS_XP + 2ull*NWG*NM*SLICE)  // 84214784

typedef __attribute__((ext_vector_type(8))) short bf16x8;
typedef __attribute__((ext_vector_type(4))) float f32x4;

__device__ __forceinline__ unsigned short f2bf(float f) {
  unsigned u = __float_as_uint(f);
  u += 0x7FFFu + ((u >> 16) & 1u);   // round-nearest-even
  return (unsigned short)(u >> 16);
}
__device__ __forceinline__ float bf2f(unsigned short h) {
  return __uint_as_float(((unsigned)h) << 16);
}
__device__ __forceinline__ float sigmoidf_(float x) {
  return 1.0f / (1.0f + expf(-x));
}

// All-to-all flag barrier: wg i release-stores flags[i]=n; threads 0..255 each poll one flag.
__device__ __forceinline__ void gbar(unsigned* flags, unsigned n) {
  __threadfence();
  __syncthreads();
  if (threadIdx.x == 0)
    __hip_atomic_store(&flags[blockIdx.x], n, __ATOMIC_RELEASE, __HIP_MEMORY_SCOPE_AGENT);
  if (threadIdx.x < NWG) {
    while (__hip_atomic_load(&flags[threadIdx.x], __ATOMIC_ACQUIRE, __HIP_MEMORY_SCOPE_AGENT) < n)
      __builtin_amdgcn_s_sleep(1);
  }
  __threadfence();
  __syncthreads();
}

#define MFMA(a,b,c) __builtin_amdgcn_mfma_f32_16x16x32_bf16((a),(b),(c),0,0,0)

__global__ void __launch_bounds__(NTH)
lstm_all(const int* __restrict__ x, const float* __restrict__ emb,
         const float* __restrict__ w_ih0, const float* __restrict__ w_hh0,
         const float* __restrict__ b_ih0, const float* __restrict__ b_hh0,
         const float* __restrict__ w_ih1, const float* __restrict__ w_hh1,
         const float* __restrict__ b_ih1, const float* __restrict__ b_hh1,
         const float* __restrict__ fc_w, const float* __restrict__ fc_b,
         float* __restrict__ out, unsigned char* __restrict__ wsb)
{
  // LDS: 3 hidden-size weight slices + 1 embed-size slice + bias + gate partial buffers
  __shared__ unsigned short sW[3*SLICE*RHH + SLICE*RIH0];  // 116736 B
  __shared__ float sB1[SLICE];
  __shared__ float sG0[NB][SLICE];
  __shared__ float sG1a[NB][SLICE];
  __shared__ float sG1b[NB][SLICE];

  const int wg  = blockIdx.x;
  const int tid = threadIdx.x;
  unsigned* flags = (unsigned*)(wsb + WS_FLAGS);
  unsigned short* h0b0 = (unsigned short*)(wsb + WS_H0);
  unsigned short* h0b1 = h0b0 + NB*NH;
  unsigned short* h1b0 = (unsigned short*)(wsb + WS_H1);
  unsigned short* h1b1 = h1b0 + NB*NH;
  unsigned* counts = (unsigned*)(wsb + WS_CNT);
  unsigned short* xs0 = (unsigned short*)(wsb + WS_XS0);
  unsigned short* xp  = (unsigned short*)(wsb + WS_XP);

  // ---------------- phase 1: gather + weight staging + histogram ----------------
  // 1a: xs0[m=t*64+b][e] = bf16(emb[x[b][t]][e])
  for (int i = wg*NTH + tid; i < NM*(NE/8); i += NWG*NTH) {
    int m = i >> 6;              // NE/8 = 64 vec8 per row
    int e8 = (i & 63) << 3;
    int t = m >> 6, b = m & 63;
    int tok = x[b*NT + t];
    const float* s = emb + (size_t)tok*NE + e8;
    float4 f0 = *(const float4*)s;
    float4 f1 = *(const float4*)(s + 4);
    bf16x8 v;
    v[0]=(short)f2bf(f0.x); v[1]=(short)f2bf(f0.y); v[2]=(short)f2bf(f0.z); v[3]=(short)f2bf(f0.w);
    v[4]=(short)f2bf(f1.x); v[5]=(short)f2bf(f1.y); v[6]=(short)f2bf(f1.z); v[7]=(short)f2bf(f1.w);
    *(bf16x8*)(xs0 + (size_t)m*NE + e8) = v;
  }
  // 1b: per-wg weight slices -> LDS (slice row sr: gate=sr>>2, unit=sr&3)
  for (int i = tid; i < SLICE*(NH/8); i += NTH) {
    int sr = i >> 7;             // NH/8 = 128
    int k8 = (i & 127) << 3;
    int gr = (sr >> 2)*NH + wg*4 + (sr & 3);
    const float* p0 = w_hh0 + (size_t)gr*NH + k8;
    const float* p1 = w_ih1 + (size_t)gr*NH + k8;
    const float* p2 = w_hh1 + (size_t)gr*NH + k8;
    float4 a0 = *(const float4*)p0, a1 = *(const float4*)(p0+4);
    float4 b0 = *(const float4*)p1, b1 = *(const float4*)(p1+4);
    float4 c0 = *(const float4*)p2, c1 = *(const float4*)(p2+4);
    bf16x8 v;
    v[0]=(short)f2bf(a0.x); v[1]=(short)f2bf(a0.y); v[2]=(short)f2bf(a0.z); v[3]=(short)f2bf(a0.w);
    v[4]=(short)f2bf(a1.x); v[5]=(short)f2bf(a1.y); v[6]=(short)f2bf(a1.z); v[7]=(short)f2bf(a1.w);
    *(bf16x8*)(&sW[0*SLICE*RHH + sr*RHH + k8]) = v;
    v[0]=(short)f2bf(b0.x); v[1]=(short)f2bf(b0.y); v[2]=(short)f2bf(b0.z); v[3]=(short)f2bf(b0.w);
    v[4]=(short)f2bf(b1.x); v[5]=(short)f2bf(b1.y); v[6]=(short)f2bf(b1.z); v[7]=(short)f2bf(b1.w);
    *(bf16x8*)(&sW[1*SLICE*RHH + sr*RHH + k8]) = v;
    v[0]=(short)f2bf(c0.x); v[1]=(short)f2bf(c0.y); v[2]=(short)f2bf(c0.z); v[3]=(short)f2bf(c0.w);
    v[4]=(short)f2bf(c1.x); v[5]=(short)f2bf(c1.y); v[6]=(short)f2bf(c1.z); v[7]=(short)f2bf(c1.w);
    *(bf16x8*)(&sW[2*SLICE*RHH + sr*RHH + k8]) = v;
  }
  for (int i = tid; i < SLICE*(NE/8); i += NTH) {
    int sr = i >> 6;             // NE/8 = 64
    int k8 = (i & 63) << 3;
    int gr = (sr >> 2)*NH + wg*4 + (sr & 3);
    const float* p = w_ih0 + (size_t)gr*NE + k8;
    float4 a0 = *(const float4*)p, a1 = *(const float4*)(p+4);
    bf16x8 v;
    v[0]=(short)f2bf(a0.x); v[1]=(short)f2bf(a0.y); v[2]=(short)f2bf(a0.z); v[3]=(short)f2bf(a0.w);
    v[4]=(short)f2bf(a1.x); v[5]=(short)f2bf(a1.y); v[6]=(short)f2bf(a1.z); v[7]=(short)f2bf(a1.w);
    *(bf16x8*)(&sW[3*SLICE*RHH + sr*RIH0 + k8]) = v;
  }
  if (tid < SLICE) {
    int gr = (tid >> 2)*NH + wg*4 + (tid & 3);
    sB1[tid] = b_ih1[gr] + b_hh1[gr];
  }
  // 1c: token histogram (counts zeroed by host memset)
  {
    int i = wg*NTH + tid;
    if (i < NB*NT) {
      int b = i >> 7;
      atomicAdd(&counts[(size_t)b*NV + x[i]], 1u);
    }
  }
  unsigned bar = 1;
  gbar(flags, bar);

  const int wave = tid >> 6, lane = tid & 63;
  const int lr = lane & 15, lq = lane >> 4;

  // ---------------- phase 2: xproj0 = xs0 @ w_ih0^T + b (sliced, bf16 out) ----------------
  {
    const unsigned short* bp = &sW[3*SLICE*RHH + lr*RIH0 + lq*8];
    int gr = (lr >> 2)*NH + wg*4 + (lr & 3);
    float biasc = b_ih0[gr] + b_hh0[gr];
    for (int mt = wave; mt < NM/16; mt += 8) {
      const unsigned short* ap = xs0 + (size_t)(mt*16 + lr)*NE + lq*8;
      f32x4 acc = {0.f,0.f,0.f,0.f};
      #pragma unroll 8
      for (int k = 0; k < NE; k += 32) {
        bf16x8 af = *(const bf16x8*)(ap + k);
        bf16x8 bfv = *(const bf16x8*)(bp + k);
        acc = MFMA(af, bfv, acc);
      }
      #pragma unroll
      for (int r = 0; r < 4; ++r) {
        int row = lq*4 + r;
        xp[((size_t)wg*NM + (size_t)mt*16 + row)*SLICE + lr] = f2bf(acc[r] + biasc);
      }
    }
  }
  gbar(flags, ++bar);

  // ---------------- phase 3: pipelined 2-layer scan, 129 grid steps ----------------
  float c_reg = 0.f;                 // tid<256: layer0 cell state; tid>=256: layer1
  const int cb = (tid & 255) >> 2, cu = tid & 3;
  {
    unsigned short* h0bufs[2] = {h0b0, h0b1};
    unsigned short* h1bufs[2] = {h1b0, h1b1};
    for (int t = 0; t <= NT; ++t) {
      if (wave < 4) {
        // A = h0[t-1]; acc0 vs w_hh0 (layer0 gates t), acc1 vs w_ih1 (layer1 x-contrib t-1)
        const unsigned short* A  = h0bufs[(t+1)&1] + (size_t)(wave*16 + lr)*NH + lq*8;
        const unsigned short* B0 = &sW[0*SLICE*RHH + lr*RHH + lq*8];
        const unsigned short* B1 = &sW[1*SLICE*RHH + lr*RHH + lq*8];
        f32x4 a0 = {0.f,0.f,0.f,0.f}, a1 = {0.f,0.f,0.f,0.f};
        if (t >= 1 && t < NT) {
          #pragma unroll 8
          for (int k = 0; k < NH; k += 32) {
            bf16x8 af = *(const bf16x8*)(A + k);
            a0 = MFMA(af, *(const bf16x8*)(B0 + k), a0);
            a1 = MFMA(af, *(const bf16x8*)(B1 + k), a1);
          }
        } else if (t < NT) {       // t == 0: only layer0
          #pragma unroll 8
          for (int k = 0; k < NH; k += 32) {
            bf16x8 af = *(const bf16x8*)(A + k);
            a0 = MFMA(af, *(const bf16x8*)(B0 + k), a0);
          }
        } else {                   // t == NT: only layer1 x-contrib
          #pragma unroll 8
          for (int k = 0; k < NH; k += 32) {
            bf16x8 af = *(const bf16x8*)(A + k);
            a1 = MFMA(af, *(const bf16x8*)(B1 + k), a1);
          }
        }
        if (t < NT) {
          #pragma unroll
          for (int r = 0; r < 4; ++r) sG0[wave*16 + lq*4 + r][lr] = a0[r];
        }
        if (t >= 1) {
          #pragma unroll
          for (int r = 0; r < 4; ++r) sG1a[wave*16 + lq*4 + r][lr] = a1[r];
        }
      } else {
        // A = h1[t-2]; acc vs w_hh1
        if (t >= 1) {
          const unsigned short* A  = h1bufs[t&1] + (size_t)((wave-4)*16 + lr)*NH + lq*8;
          const unsigned short* B2 = &sW[2*SLICE*RHH + lr*RHH + lq*8];
          f32x4 a2 = {0.f,0.f,0.f,0.f};
          #pragma unroll 8
          for (int k = 0; k < NH; k += 32) {
            bf16x8 af = *(const bf16x8*)(A + k);
            a2 = MFMA(af, *(const bf16x8*)(B2 + k), a2);
          }
          #pragma unroll
          for (int r = 0; r < 4; ++r) sG1b[(wave-4)*16 + lq*4 + r][lr] = a2[r];
        }
      }
      __syncthreads();
      // cells: thread owns (batch cb, unit cu) of its layer; c stays in a register
      if (tid < 256) {
        if (t < NT) {
          const unsigned short* q = xp + ((size_t)wg*NM + (size_t)t*64 + cb)*SLICE;
          float gi = sG0[cb][cu]      + bf2f(q[cu]);
          float gf = sG0[cb][4+cu]    + bf2f(q[4+cu]);
          float gg = sG0[cb][8+cu]    + bf2f(q[8+cu]);
          float go = sG0[cb][12+cu]   + bf2f(q[12+cu]);
          float ii = sigmoidf_(gi), ff = sigmoidf_(gf), g = tanhf(gg), oo = sigmoidf_(go);
          c_reg = ff*c_reg + ii*g;
          float h = oo * tanhf(c_reg);
          h0bufs[t&1][(size_t)cb*NH + wg*4 + cu] = f2bf(h);
        }
      } else {
        if (t >= 1) {
          float gi = sG1a[cb][cu]    + sG1b[cb][cu]    + sB1[cu];
          float gf = sG1a[cb][4+cu]  + sG1b[cb][4+cu]  + sB1[4+cu];
          float gg = sG1a[cb][8+cu]  + sG1b[cb][8+cu]  + sB1[8+cu];
          float go = sG1a[cb][12+cu] + sG1b[cb][12+cu] + sB1[12+cu];
          float ii = sigmoidf_(gi), ff = sigmoidf_(gf), g = tanhf(gg), oo = sigmoidf_(go);
          c_reg = ff*c_reg + ii*g;
          float h = oo * tanhf(c_reg);
          h1bufs[(t+1)&1][(size_t)cb*NH + wg*4 + cu] = f2bf(h);
        }
      }
      gbar(flags, ++bar);
    }
  }

  // ---------------- phase 4: FC + repetition penalty (h1[127] in h1b1) ----------------
  {
    const unsigned short* h1 = h1b1;
    int tile = wg*8 + wave;                    // 2048 waves, 2000 col-tiles of 16
    if (tile < NV/16) {
      int c0 = tile*16;
      const float* wb = fc_w + (size_t)(c0 + lr)*NH + lq*8;
      const unsigned short* ab = h1 + (size_t)lr*NH + lq*8;
      f32x4 acc[4] = {{0.f,0.f,0.f,0.f},{0.f,0.f,0.f,0.f},{0.f,0.f,0.f,0.f},{0.f,0.f,0.f,0.f}};
      #pragma unroll 4
      for (int k = 0; k < NH; k += 32) {
        float4 w0 = *(const float4*)(wb + k);
        float4 w1 = *(const float4*)(wb + k + 4);
        bf16x8 bfv;
        bfv[0]=(short)f2bf(w0.x); bfv[1]=(short)f2bf(w0.y); bfv[2]=(short)f2bf(w0.z); bfv[3]=(short)f2bf(w0.w);
        bfv[4]=(short)f2bf(w1.x); bfv[5]=(short)f2bf(w1.y); bfv[6]=(short)f2bf(w1.z); bfv[7]=(short)f2bf(w1.w);
        #pragma unroll
        for (int mt = 0; mt < 4; ++mt) {
          bf16x8 af = *(const bf16x8*)(ab + (size_t)mt*16*NH + k);
          acc[mt] = MFMA(af, bfv, acc[mt]);
        }
      }
      int c = c0 + lr;
      float fb = fc_b[c];
      #pragma unroll
      for (int mt = 0; mt < 4; ++mt) {
        #pragma unroll
        for (int r = 0; r < 4; ++r) {
          int b = mt*16 + lq*4 + r;
          unsigned cnt = counts[(size_t)b*NV + c];
          float v = (acc[mt][r] + fb) * exp2f(-0.26303440583379378f * (float)cnt);
          out[(size_t)b*NV + c] = v;
        }
      }
    }
  }
}

extern "C" void kernel_launch(void* const* d_in, const int* in_sizes, int n_in,
                              void* d_out, int out_size, void* d_ws, size_t ws_size,
                              hipStream_t stream) {
  const int*   x     = (const int*)  d_in[0];
  const float* emb   = (const float*)d_in[1];
  const float* w_ih0 = (const float*)d_in[2];
  const float* w_hh0 = (const float*)d_in[3];
  const float* b_ih0 = (const float*)d_in[4];
  const float* b_hh0 = (const float*)d_in[5];
  const float* w_ih1 = (const float*)d_in[6];
  const float* w_hh1 = (const float*)d_in[7];
  const float* b_ih1 = (const float*)d_in[8];
  const float* b_hh1 = (const float*)d_in[9];
  const float* fc_w  = (const float*)d_in[10];
  const float* fc_b  = (const float*)d_in[11];
  if (ws_size < WS_NEEDED) return;
  hipMemsetAsync(d_ws, 0, WS_ZERO_END, stream);  // flags + h buffers + counts
  hipLaunchKernelGGL(lstm_all, dim3(NWG), dim3(NTH), 0, stream,
                     x, emb, w_ih0, w_hh0, b_ih0, b_hh0,
                     w_ih1, w_hh1, b_ih1, b_hh1, fc_w, fc_b,
                     (float*)d_out, (unsigned char*)d_ws);
}

// Round 3
// 2097.104 us; speedup vs baseline: 6.7498x; 6.7498x over previous
//
#include <hip/hip_runtime.h>
#include <hip/hip_bf16.h>
#include <stdint.h>

// Problem constants
#define NB 64      // batch
#define NT 128     // seq len
#define NE 512     // embed
#define NH 1024    // hidden
#define NV 32000   // vocab
#define NM (NB*NT) // 8192 flattened (t-major: m = t*64 + b)

// Kernel config
#define NWG 256    // one workgroup per CU, all co-resident
#define NTH 512    // 8 waves

// ws byte offsets. History slots are write-once per launch: slot s of hist0
// holds h0[s-1] (slot 0 = zeros); hist1 slot s holds h1[s-1].
#define HSLOT_B (NB*NH*2u)                      // 131072 B per history slot
#define WS_FLAGS   0u
#define WS_H0      4096u
#define WS_H1      (WS_H0 + 129u*HSLOT_B)       // 16912384
#define WS_CNT     (WS_H1 + 129u*HSLOT_B)       // 33820672
#define WS_XS0     (WS_CNT + 4u*NB*NV)          // 42012672
#define WS_NEEDED  (WS_XS0 + 2u*NM*NE)          // 50401280

typedef __attribute__((ext_vector_type(8))) short bf16x8;
typedef __attribute__((ext_vector_type(4))) float f32x4;

__device__ __forceinline__ unsigned short f2bf(float f) {
  unsigned u = __float_as_uint(f);
  u += 0x7FFFu + ((u >> 16) & 1u);   // round-nearest-even
  return (unsigned short)(u >> 16);
}
__device__ __forceinline__ float bf2f(unsigned short h) {
  return __uint_as_float(((unsigned)h) << 16);
}
__device__ __forceinline__ float sigmoidf_(float x) {
  return 1.0f / (1.0f + expf(-x));
}
__device__ __forceinline__ bf16x8 pack8(float4 a, float4 b) {
  bf16x8 v;
  v[0]=(short)f2bf(a.x); v[1]=(short)f2bf(a.y); v[2]=(short)f2bf(a.z); v[3]=(short)f2bf(a.w);
  v[4]=(short)f2bf(b.x); v[5]=(short)f2bf(b.y); v[6]=(short)f2bf(b.z); v[7]=(short)f2bf(b.w);
  return v;
}

// Light grid barrier: NO fences, NO acquire/release cache maintenance.
// __syncthreads drains each wave's vmcnt (so all sc1 data stores have
// completed at the LLC) before thread 0 publishes the flag. Pollers use
// relaxed agent-scope loads (sc1, straight to LLC, no buffer_inv per poll).
__device__ __forceinline__ void gbar_light(unsigned* flags, unsigned n) {
  __syncthreads();
  if (threadIdx.x == 0)
    __hip_atomic_store(&flags[blockIdx.x], n, __ATOMIC_RELAXED, __HIP_MEMORY_SCOPE_AGENT);
  if (threadIdx.x < 64) {
    #pragma unroll
    for (int j = 0; j < 4; ++j) {
      while (__hip_atomic_load(&flags[threadIdx.x + j*64], __ATOMIC_RELAXED, __HIP_MEMORY_SCOPE_AGENT) < n)
        __builtin_amdgcn_s_sleep(1);
    }
  }
  __syncthreads();
}

#define MFMA(a,b,c) __builtin_amdgcn_mfma_f32_16x16x32_bf16((a),(b),(c),0,0,0)

__global__ void __launch_bounds__(NTH, 2)
lstm_all(const int* __restrict__ x, const float* __restrict__ emb,
         const float* __restrict__ w_ih0, const float* __restrict__ w_hh0,
         const float* __restrict__ b_ih0, const float* __restrict__ b_hh0,
         const float* __restrict__ w_ih1, const float* __restrict__ w_hh1,
         const float* __restrict__ b_ih1, const float* __restrict__ b_hh1,
         const float* __restrict__ fc_w, const float* __restrict__ fc_b,
         float* __restrict__ out, unsigned char* __restrict__ wsb)
{
  // LDS (~65 KB): w_ih1/w_ih0 slices in MFMA-fragment-contiguous order
  // (elem (kk,lane,j) at [(kk*64+lane)*8+j] -> conflict-free ds_read_b128),
  // gate partial buffers, h staging, biases.
  __shared__ unsigned short sWih1[32*64*8];            // 32 KB
  __shared__ unsigned short sWih0[16*64*8];            // 16 KB
  __shared__ float sG0[NB][16], sG1a[NB][16], sG1b[NB][16], sGih[NB][16];
  __shared__ float sB0[16], sB1[16];
  __shared__ alignas(8) unsigned short sH0[NB][4], sH1[NB][4];

  const int wg  = blockIdx.x;
  const int tid = threadIdx.x;
  const int wave = tid >> 6, lane = tid & 63;
  const int lr = lane & 15, lq = lane >> 4;

  unsigned* flags = (unsigned*)(wsb + WS_FLAGS);
  unsigned short* hist0 = (unsigned short*)(wsb + WS_H0);
  unsigned short* hist1 = (unsigned short*)(wsb + WS_H1);
  unsigned* counts = (unsigned*)(wsb + WS_CNT);
  unsigned short* xs0 = (unsigned short*)(wsb + WS_XS0);

  // gate-row this lane's B-fragments correspond to: gate=(lr>>2), unit=(lr&3)
  const int gr = (lr >> 2)*NH + wg*4 + (lr & 3);

  // ---- phase 1a: step-invariant B-fragments of w_hh0 (waves 0-3) or w_hh1
  // (waves 4-7) into 128 VGPRs. breg[kk][j] = bf16(W[gr][kk*32 + lq*8 + j]).
  bf16x8 breg[32];
  {
    const float* wsrc = (wave < 4 ? w_hh0 : w_hh1) + (size_t)gr*NH + lq*8;
    #pragma unroll
    for (int kk = 0; kk < 32; ++kk)
      breg[kk] = pack8(*(const float4*)(wsrc + kk*32), *(const float4*)(wsrc + kk*32 + 4));
  }

  // ---- phase 1b: gather embeddings -> xs0 (bf16, t-major), published sc1
  for (int i = wg*NTH + tid; i < NM*(NE/8); i += NWG*NTH) {
    int m = i >> 6;              // NE/8 = 64 vec8 per row
    int e8 = (i & 63) << 3;
    int t = m >> 6, b = m & 63;
    int tok = x[b*NT + t];
    const float* s = emb + (size_t)tok*NE + e8;
    union { bf16x8 v8; unsigned long long u[2]; } u;
    u.v8 = pack8(*(const float4*)s, *(const float4*)(s + 4));
    unsigned long long* dst = (unsigned long long*)(xs0 + (size_t)m*NE + e8);
    __hip_atomic_store(dst,   u.u[0], __ATOMIC_RELAXED, __HIP_MEMORY_SCOPE_AGENT);
    __hip_atomic_store(dst+1, u.u[1], __ATOMIC_RELAXED, __HIP_MEMORY_SCOPE_AGENT);
  }

  // ---- phase 1c: w_ih1 / w_ih0 slices -> LDS in fragment order
  for (int i = tid; i < 32*64; i += NTH) {      // w_ih1: kk<32
    int kk = i >> 6, l = i & 63;
    int glr = l & 15, glq = l >> 4;
    int ggr = (glr >> 2)*NH + wg*4 + (glr & 3);
    const float* p = w_ih1 + (size_t)ggr*NH + kk*32 + glq*8;
    ((bf16x8*)sWih1)[i] = pack8(*(const float4*)p, *(const float4*)(p + 4));
  }
  for (int i = tid; i < 16*64; i += NTH) {      // w_ih0: kk<16 (K=512)
    int kk = i >> 6, l = i & 63;
    int glr = l & 15, glq = l >> 4;
    int ggr = (glr >> 2)*NH + wg*4 + (glr & 3);
    const float* p = w_ih0 + (size_t)ggr*NE + kk*32 + glq*8;
    ((bf16x8*)sWih0)[i] = pack8(*(const float4*)p, *(const float4*)(p + 4));
  }
  if (tid < 16) {
    int g2 = (tid >> 2)*NH + wg*4 + (tid & 3);
    sB0[tid] = b_ih0[g2] + b_hh0[g2];
    sB1[tid] = b_ih1[g2] + b_hh1[g2];
  }
  // ---- phase 1d: token histogram (counts zeroed by host memset)
  {
    int i = wg*NTH + tid;
    if (i < NB*NT) {
      int b = i >> 7;
      atomicAdd(&counts[(size_t)b*NV + x[i]], 1u);
    }
  }
  unsigned bar = 1;
  gbar_light(flags, bar);

  // ---- phase 3: pipelined 2-layer scan, 129 grid steps ----
  // step t: waves 0-3: a0 = h0[t-1]@w_hh0^T (regs), a1 = h0[t-1]@w_ih1^T (LDS)
  //         waves 4-7: a2 = h1[t-2]@w_hh1^T (regs), aih = xs0[t]@w_ih0^T (LDS)
  // cells tid<256: layer0 time t (a0+aih+b0);  tid>=256: layer1 time t-1 (a1+a2+b1)
  float c_reg = 0.f;
  const int cb = (tid & 255) >> 2, cu = tid & 3;
  for (int t = 0; t <= NT; ++t) {
    if (wave < 4) {
      const unsigned short* A = hist0 + (size_t)t*(NB*NH) + (size_t)(wave*16 + lr)*NH + lq*8;
      f32x4 a0 = {0.f,0.f,0.f,0.f}, a1 = {0.f,0.f,0.f,0.f};
      #pragma unroll
      for (int kk = 0; kk < 32; ++kk) {
        bf16x8 af = *(const bf16x8*)(A + kk*32);     // plain load, L2-cached (write-once slot)
        a0 = MFMA(af, breg[kk], a0);
        a1 = MFMA(af, ((const bf16x8*)sWih1)[kk*64 + lane], a1);
      }
      #pragma unroll
      for (int r = 0; r < 4; ++r) {
        sG0 [wave*16 + lq*4 + r][lr] = a0[r];
        sG1a[wave*16 + lq*4 + r][lr] = a1[r];
      }
    } else {
      if (t >= 1) {
        const unsigned short* A = hist1 + (size_t)(t-1)*(NB*NH) + (size_t)((wave-4)*16 + lr)*NH + lq*8;
        f32x4 a2 = {0.f,0.f,0.f,0.f};
        #pragma unroll
        for (int kk = 0; kk < 32; ++kk)
          a2 = MFMA(*(const bf16x8*)(A + kk*32), breg[kk], a2);
        #pragma unroll
        for (int r = 0; r < 4; ++r) sG1b[(wave-4)*16 + lq*4 + r][lr] = a2[r];
      }
      if (t < NT) {
        const unsigned short* A = xs0 + (size_t)(t*64 + (wave-4)*16 + lr)*NE + lq*8;
        f32x4 ai = {0.f,0.f,0.f,0.f};
        #pragma unroll
        for (int kk = 0; kk < 16; ++kk)
          ai = MFMA(*(const bf16x8*)(A + kk*32), ((const bf16x8*)sWih0)[kk*64 + lane], ai);
        #pragma unroll
        for (int r = 0; r < 4; ++r) sGih[(wave-4)*16 + lq*4 + r][lr] = ai[r];
      }
    }
    __syncthreads();
    if (tid < 256) {
      if (t < NT) {
        float gi = sG0[cb][cu]    + sGih[cb][cu]    + sB0[cu];
        float gf = sG0[cb][4+cu]  + sGih[cb][4+cu]  + sB0[4+cu];
        float gg = sG0[cb][8+cu]  + sGih[cb][8+cu]  + sB0[8+cu];
        float go = sG0[cb][12+cu] + sGih[cb][12+cu] + sB0[12+cu];
        float ii = sigmoidf_(gi), ff = sigmoidf_(gf), g = tanhf(gg), oo = sigmoidf_(go);
        c_reg = ff*c_reg + ii*g;
        sH0[cb][cu] = f2bf(oo * tanhf(c_reg));
      }
    } else {
      if (t >= 1) {
        float gi = sG1a[cb][cu]    + sG1b[cb][cu]    + sB1[cu];
        float gf = sG1a[cb][4+cu]  + sG1b[cb][4+cu]  + sB1[4+cu];
        float gg = sG1a[cb][8+cu]  + sG1b[cb][8+cu]  + sB1[8+cu];
        float go = sG1a[cb][12+cu] + sG1b[cb][12+cu] + sB1[12+cu];
        float ii = sigmoidf_(gi), ff = sigmoidf_(gf), g = tanhf(gg), oo = sigmoidf_(go);
        c_reg = ff*c_reg + ii*g;
        sH1[cb][cu] = f2bf(oo * tanhf(c_reg));
      }
    }
    __syncthreads();
    // publish h slices: 8 B per batch row via relaxed agent (sc1) atomic stores
    if (wave == 0 && t < NT) {
      unsigned long long v = *(const unsigned long long*)&sH0[lane][0];
      __hip_atomic_store((unsigned long long*)(hist0 + (size_t)(t+1)*(NB*NH) + (size_t)lane*NH + wg*4),
                         v, __ATOMIC_RELAXED, __HIP_MEMORY_SCOPE_AGENT);
    }
    if (wave == 1 && t >= 1) {
      unsigned long long v = *(const unsigned long long*)&sH1[lane][0];
      __hip_atomic_store((unsigned long long*)(hist1 + (size_t)t*(NB*NH) + (size_t)lane*NH + wg*4),
                         v, __ATOMIC_RELAXED, __HIP_MEMORY_SCOPE_AGENT);
    }
    gbar_light(flags, ++bar);
  }

  // ---- phase 4: FC + repetition penalty (h1[127] = hist1 slot 128) ----
  {
    const unsigned short* h1 = hist1 + (size_t)128*(NB*NH);
    int tile = wg*8 + wave;                    // 2048 waves, 2000 col-tiles of 16
    if (tile < NV/16) {
      int c0 = tile*16;
      const float* wb = fc_w + (size_t)(c0 + lr)*NH + lq*8;
      const unsigned short* ab = h1 + (size_t)lr*NH + lq*8;
      f32x4 acc[4] = {{0.f,0.f,0.f,0.f},{0.f,0.f,0.f,0.f},{0.f,0.f,0.f,0.f},{0.f,0.f,0.f,0.f}};
      #pragma unroll 4
      for (int k = 0; k < NH; k += 32) {
        bf16x8 bfv = pack8(*(const float4*)(wb + k), *(const float4*)(wb + k + 4));
        #pragma unroll
        for (int mt = 0; mt < 4; ++mt) {
          bf16x8 af = *(const bf16x8*)(ab + (size_t)mt*16*NH + k);
          acc[mt] = MFMA(af, bfv, acc[mt]);
        }
      }
      int c = c0 + lr;
      float fb = fc_b[c];
      #pragma unroll
      for (int mt = 0; mt < 4; ++mt) {
        #pragma unroll
        for (int r = 0; r < 4; ++r) {
          int b = mt*16 + lq*4 + r;
          unsigned cnt = counts[(size_t)b*NV + c];
          float v = (acc[mt][r] + fb) * exp2f(-0.26303440583379378f * (float)cnt);
          out[(size_t)b*NV + c] = v;
        }
      }
    }
  }
}

extern "C" void kernel_launch(void* const* d_in, const int* in_sizes, int n_in,
                              void* d_out, int out_size, void* d_ws, size_t ws_size,
                              hipStream_t stream) {
  const int*   x     = (const int*)  d_in[0];
  const float* emb   = (const float*)d_in[1];
  const float* w_ih0 = (const float*)d_in[2];
  const float* w_hh0 = (const float*)d_in[3];
  const float* b_ih0 = (const float*)d_in[4];
  const float* b_hh0 = (const float*)d_in[5];
  const float* w_ih1 = (const float*)d_in[6];
  const float* w_hh1 = (const float*)d_in[7];
  const float* b_ih1 = (const float*)d_in[8];
  const float* b_hh1 = (const float*)d_in[9];
  const float* fc_w  = (const float*)d_in[10];
  const float* fc_b  = (const float*)d_in[11];
  if (ws_size < WS_NEEDED) return;
  unsigned char* ws = (unsigned char*)d_ws;
  hipMemsetAsync(ws + WS_FLAGS, 0, 4096, stream);              // barrier flags
  hipMemsetAsync(ws + WS_H0, 0, HSLOT_B, stream);              // h0 init slot (zeros)
  hipMemsetAsync(ws + WS_H1, 0, HSLOT_B, stream);              // h1 init slot (zeros)
  hipMemsetAsync(ws + WS_CNT, 0, 4u*NB*NV, stream);            // token histogram
  hipLaunchKernelGGL(lstm_all, dim3(NWG), dim3(NTH), 0, stream,
                     x, emb, w_ih0, w_hh0, b_ih0, b_hh0,
                     w_ih1, w_hh1, b_ih1, b_hh1, fc_w, fc_b,
                     (float*)d_out, (unsigned char*)d_ws);
}

// Round 4
// 1763.646 us; speedup vs baseline: 8.0260x; 1.1891x over previous
//
#include <hip/hip_runtime.h>
#include <hip/hip_bf16.h>
#include <stdint.h>

// Problem constants
#define NB 64      // batch
#define NT 128     // seq len
#define NE 512     // embed
#define NH 1024    // hidden
#define NV 32000   // vocab
#define NM (NB*NT) // 8192 flattened (t-major: m = t*64 + b)

// Kernel config
#define NWG 256    // one workgroup per CU, all co-resident
#define NTH 512    // 8 waves
#define FLAG_STRIDE 32u   // one flag per 128-B LLC line (poll-contention fix)

// ws byte offsets. History slots are write-once per launch: slot s of hist0
// holds h0[s-1] (slot 0 = zeros); hist1 slot s holds h1[s-1].
#define HSLOT_B (NB*NH*2u)                      // 131072 B per history slot
#define WS_FLAGS   0u
#define WS_FLAG_B  (NWG*FLAG_STRIDE*4u)         // 32768 B
#define WS_H0      WS_FLAG_B
#define WS_H1      (WS_H0 + 129u*HSLOT_B)       // 16941056
#define WS_CNT     (WS_H1 + 129u*HSLOT_B)       // 33849344
#define WS_XS0     (WS_CNT + 4u*NB*NV)          // 42041344
#define WS_NEEDED  (WS_XS0 + 2u*NM*NE)          // 50429952

typedef __attribute__((ext_vector_type(8))) short bf16x8;
typedef __attribute__((ext_vector_type(4))) float f32x4;

__device__ __forceinline__ unsigned short f2bf(float f) {
  unsigned u = __float_as_uint(f);
  u += 0x7FFFu + ((u >> 16) & 1u);   // round-nearest-even
  return (unsigned short)(u >> 16);
}
__device__ __forceinline__ float bf2f(unsigned short h) {
  return __uint_as_float(((unsigned)h) << 16);
}
__device__ __forceinline__ float sigmoidf_(float x) {
  return 1.0f / (1.0f + expf(-x));
}
__device__ __forceinline__ bf16x8 pack8(float4 a, float4 b) {
  bf16x8 v;
  v[0]=(short)f2bf(a.x); v[1]=(short)f2bf(a.y); v[2]=(short)f2bf(a.z); v[3]=(short)f2bf(a.w);
  v[4]=(short)f2bf(b.x); v[5]=(short)f2bf(b.y); v[6]=(short)f2bf(b.z); v[7]=(short)f2bf(b.w);
  return v;
}

// Light grid barrier: NO fences, NO acquire/release cache maintenance.
// __syncthreads drains each wave's vmcnt (so all sc1 data stores have
// completed at the LLC) before thread 0 publishes the flag. Pollers use
// relaxed agent-scope loads (sc1, straight to LLC, no buffer_inv per poll).
// Flags are padded to one per 128-B line so the 16k concurrent pollers
// spread across 256 LLC lines instead of hammering ~32.
__device__ __forceinline__ void gbar_light(unsigned* flags, unsigned n) {
  __syncthreads();
  if (threadIdx.x == 0)
    __hip_atomic_store(&flags[(unsigned)blockIdx.x * FLAG_STRIDE], n,
                       __ATOMIC_RELAXED, __HIP_MEMORY_SCOPE_AGENT);
  if (threadIdx.x < 64) {
    #pragma unroll
    for (int j = 0; j < 4; ++j) {
      while (__hip_atomic_load(&flags[(threadIdx.x + j*64u) * FLAG_STRIDE],
                               __ATOMIC_RELAXED, __HIP_MEMORY_SCOPE_AGENT) < n)
        __builtin_amdgcn_s_sleep(2);
    }
  }
  __syncthreads();
}

#define MFMA(a,b,c) __builtin_amdgcn_mfma_f32_16x16x32_bf16((a),(b),(c),0,0,0)

__global__ void __launch_bounds__(NTH, 2)
lstm_all(const int* __restrict__ x, const float* __restrict__ emb,
         const float* __restrict__ w_ih0, const float* __restrict__ w_hh0,
         const float* __restrict__ b_ih0, const float* __restrict__ b_hh0,
         const float* __restrict__ w_ih1, const float* __restrict__ w_hh1,
         const float* __restrict__ b_ih1, const float* __restrict__ b_hh1,
         const float* __restrict__ fc_w, const float* __restrict__ fc_b,
         float* __restrict__ out, unsigned char* __restrict__ wsb)
{
  // LDS (~65 KB): w_ih1/w_ih0 slices in MFMA-fragment-contiguous order
  // (elem (kk,lane,j) at [(kk*64+lane)*8+j] -> conflict-free ds_read_b128),
  // gate partial buffers, h staging, biases.
  __shared__ unsigned short sWih1[32*64*8];            // 32 KB
  __shared__ unsigned short sWih0[16*64*8];            // 16 KB
  __shared__ float sG0[NB][16], sG1a[NB][16], sG1b[NB][16], sGih[NB][16];
  __shared__ float sB0[16], sB1[16];
  __shared__ alignas(8) unsigned short sH0[NB][4], sH1[NB][4];

  const int wg  = blockIdx.x;
  const int tid = threadIdx.x;
  const int wave = tid >> 6, lane = tid & 63;
  const int lr = lane & 15, lq = lane >> 4;

  unsigned* flags = (unsigned*)(wsb + WS_FLAGS);
  unsigned short* hist0 = (unsigned short*)(wsb + WS_H0);
  unsigned short* hist1 = (unsigned short*)(wsb + WS_H1);
  unsigned* counts = (unsigned*)(wsb + WS_CNT);
  unsigned short* xs0 = (unsigned short*)(wsb + WS_XS0);

  // gate-row this lane's B-fragments correspond to: gate=(lr>>2), unit=(lr&3)
  const int gr = (lr >> 2)*NH + wg*4 + (lr & 3);

  // ---- phase 1a: step-invariant B-fragments of w_hh0 (waves 0-3) or w_hh1
  // (waves 4-7) into 128 VGPRs (lands in AGPRs via unified file).
  bf16x8 breg[32];
  {
    const float* wsrc = (wave < 4 ? w_hh0 : w_hh1) + (size_t)gr*NH + lq*8;
    #pragma unroll
    for (int kk = 0; kk < 32; ++kk)
      breg[kk] = pack8(*(const float4*)(wsrc + kk*32), *(const float4*)(wsrc + kk*32 + 4));
  }

  // ---- phase 1b: gather embeddings -> xs0 (bf16, t-major), published sc1
  for (int i = wg*NTH + tid; i < NM*(NE/8); i += NWG*NTH) {
    int m = i >> 6;              // NE/8 = 64 vec8 per row
    int e8 = (i & 63) << 3;
    int t = m >> 6, b = m & 63;
    int tok = x[b*NT + t];
    const float* s = emb + (size_t)tok*NE + e8;
    union { bf16x8 v8; unsigned long long u[2]; } u;
    u.v8 = pack8(*(const float4*)s, *(const float4*)(s + 4));
    unsigned long long* dst = (unsigned long long*)(xs0 + (size_t)m*NE + e8);
    __hip_atomic_store(dst,   u.u[0], __ATOMIC_RELAXED, __HIP_MEMORY_SCOPE_AGENT);
    __hip_atomic_store(dst+1, u.u[1], __ATOMIC_RELAXED, __HIP_MEMORY_SCOPE_AGENT);
  }

  // ---- phase 1c: w_ih1 / w_ih0 slices -> LDS in fragment order
  for (int i = tid; i < 32*64; i += NTH) {      // w_ih1: kk<32
    int kk = i >> 6, l = i & 63;
    int glr = l & 15, glq = l >> 4;
    int ggr = (glr >> 2)*NH + wg*4 + (glr & 3);
    const float* p = w_ih1 + (size_t)ggr*NH + kk*32 + glq*8;
    ((bf16x8*)sWih1)[i] = pack8(*(const float4*)p, *(const float4*)(p + 4));
  }
  for (int i = tid; i < 16*64; i += NTH) {      // w_ih0: kk<16 (K=512)
    int kk = i >> 6, l = i & 63;
    int glr = l & 15, glq = l >> 4;
    int ggr = (glr >> 2)*NH + wg*4 + (glr & 3);
    const float* p = w_ih0 + (size_t)ggr*NE + kk*32 + glq*8;
    ((bf16x8*)sWih0)[i] = pack8(*(const float4*)p, *(const float4*)(p + 4));
  }
  if (tid < 16) {
    int g2 = (tid >> 2)*NH + wg*4 + (tid & 3);
    sB0[tid] = b_ih0[g2] + b_hh0[g2];
    sB1[tid] = b_ih1[g2] + b_hh1[g2];
  }
  // ---- phase 1d: token histogram (counts zeroed by host memset)
  {
    int i = wg*NTH + tid;
    if (i < NB*NT) {
      int b = i >> 7;
      atomicAdd(&counts[(size_t)b*NV + x[i]], 1u);
    }
  }
  unsigned bar = 1;
  gbar_light(flags, bar);

  // ---- phase 3: pipelined 2-layer scan, 129 grid steps ----
  // step t: waves 0-3: a0 = h0[t-1]@w_hh0^T (regs), a1 = h0[t-1]@w_ih1^T (LDS)
  //         waves 4-7: a2 = h1[t-2]@w_hh1^T (regs), aih = xs0[t]@w_ih0^T (LDS)
  // cells tid<256: layer0 time t (a0+aih+b0);  tid>=256: layer1 time t-1 (a1+a2+b1)
  float c_reg = 0.f;
  const int cb = (tid & 255) >> 2, cu = tid & 3;
  for (int t = 0; t <= NT; ++t) {
    if (wave < 4) {
      const unsigned short* A = hist0 + (size_t)t*(NB*NH) + (size_t)(wave*16 + lr)*NH + lq*8;
      f32x4 a0 = {0.f,0.f,0.f,0.f}, a1 = {0.f,0.f,0.f,0.f};
      #pragma unroll
      for (int kk = 0; kk < 32; ++kk) {
        bf16x8 af = *(const bf16x8*)(A + kk*32);     // plain load, L2-cached (write-once slot)
        a0 = MFMA(af, breg[kk], a0);
        a1 = MFMA(af, ((const bf16x8*)sWih1)[kk*64 + lane], a1);
      }
      #pragma unroll
      for (int r = 0; r < 4; ++r) {
        sG0 [wave*16 + lq*4 + r][lr] = a0[r];
        sG1a[wave*16 + lq*4 + r][lr] = a1[r];
      }
    } else {
      if (t >= 1) {
        const unsigned short* A = hist1 + (size_t)(t-1)*(NB*NH) + (size_t)((wave-4)*16 + lr)*NH + lq*8;
        f32x4 a2 = {0.f,0.f,0.f,0.f};
        #pragma unroll
        for (int kk = 0; kk < 32; ++kk)
          a2 = MFMA(*(const bf16x8*)(A + kk*32), breg[kk], a2);
        #pragma unroll
        for (int r = 0; r < 4; ++r) sG1b[(wave-4)*16 + lq*4 + r][lr] = a2[r];
      }
      if (t < NT) {
        const unsigned short* A = xs0 + (size_t)(t*64 + (wave-4)*16 + lr)*NE + lq*8;
        f32x4 ai = {0.f,0.f,0.f,0.f};
        #pragma unroll
        for (int kk = 0; kk < 16; ++kk)
          ai = MFMA(*(const bf16x8*)(A + kk*32), ((const bf16x8*)sWih0)[kk*64 + lane], ai);
        #pragma unroll
        for (int r = 0; r < 4; ++r) sGih[(wave-4)*16 + lq*4 + r][lr] = ai[r];
      }
    }
    __syncthreads();
    if (tid < 256) {
      if (t < NT) {
        float gi = sG0[cb][cu]    + sGih[cb][cu]    + sB0[cu];
        float gf = sG0[cb][4+cu]  + sGih[cb][4+cu]  + sB0[4+cu];
        float gg = sG0[cb][8+cu]  + sGih[cb][8+cu]  + sB0[8+cu];
        float go = sG0[cb][12+cu] + sGih[cb][12+cu] + sB0[12+cu];
        float ii = sigmoidf_(gi), ff = sigmoidf_(gf), g = tanhf(gg), oo = sigmoidf_(go);
        c_reg = ff*c_reg + ii*g;
        sH0[cb][cu] = f2bf(oo * tanhf(c_reg));
      }
    } else {
      if (t >= 1) {
        float gi = sG1a[cb][cu]    + sG1b[cb][cu]    + sB1[cu];
        float gf = sG1a[cb][4+cu]  + sG1b[cb][4+cu]  + sB1[4+cu];
        float gg = sG1a[cb][8+cu]  + sG1b[cb][8+cu]  + sB1[8+cu];
        float go = sG1a[cb][12+cu] + sG1b[cb][12+cu] + sB1[12+cu];
        float ii = sigmoidf_(gi), ff = sigmoidf_(gf), g = tanhf(gg), oo = sigmoidf_(go);
        c_reg = ff*c_reg + ii*g;
        sH1[cb][cu] = f2bf(oo * tanhf(c_reg));
      }
    }
    __syncthreads();
    // publish h slices: 8 B per batch row via relaxed agent (sc1) atomic stores
    if (wave == 0 && t < NT) {
      unsigned long long v = *(const unsigned long long*)&sH0[lane][0];
      __hip_atomic_store((unsigned long long*)(hist0 + (size_t)(t+1)*(NB*NH) + (size_t)lane*NH + wg*4),
                         v, __ATOMIC_RELAXED, __HIP_MEMORY_SCOPE_AGENT);
    }
    if (wave == 1 && t >= 1) {
      unsigned long long v = *(const unsigned long long*)&sH1[lane][0];
      __hip_atomic_store((unsigned long long*)(hist1 + (size_t)t*(NB*NH) + (size_t)lane*NH + wg*4),
                         v, __ATOMIC_RELAXED, __HIP_MEMORY_SCOPE_AGENT);
    }
    gbar_light(flags, ++bar);
  }

  // ---- phase 4: FC + repetition penalty (h1[127] = hist1 slot 128) ----
  {
    const unsigned short* h1 = hist1 + (size_t)128*(NB*NH);
    int tile = wg*8 + wave;                    // 2048 waves, 2000 col-tiles of 16
    if (tile < NV/16) {
      int c0 = tile*16;
      const float* wb = fc_w + (size_t)(c0 + lr)*NH + lq*8;
      const unsigned short* ab = h1 + (size_t)lr*NH + lq*8;
      f32x4 acc[4] = {{0.f,0.f,0.f,0.f},{0.f,0.f,0.f,0.f},{0.f,0.f,0.f,0.f},{0.f,0.f,0.f,0.f}};
      #pragma unroll 4
      for (int k = 0; k < NH; k += 32) {
        bf16x8 bfv = pack8(*(const float4*)(wb + k), *(const float4*)(wb + k + 4));
        #pragma unroll
        for (int mt = 0; mt < 4; ++mt) {
          bf16x8 af = *(const bf16x8*)(ab + (size_t)mt*16*NH + k);
          acc[mt] = MFMA(af, bfv, acc[mt]);
        }
      }
      int c = c0 + lr;
      float fb = fc_b[c];
      #pragma unroll
      for (int mt = 0; mt < 4; ++mt) {
        #pragma unroll
        for (int r = 0; r < 4; ++r) {
          int b = mt*16 + lq*4 + r;
          unsigned cnt = counts[(size_t)b*NV + c];
          float v = (acc[mt][r] + fb) * exp2f(-0.26303440583379378f * (float)cnt);
          out[(size_t)b*NV + c] = v;
        }
      }
    }
  }
}

extern "C" void kernel_launch(void* const* d_in, const int* in_sizes, int n_in,
                              void* d_out, int out_size, void* d_ws, size_t ws_size,
                              hipStream_t stream) {
  const int*   x     = (const int*)  d_in[0];
  const float* emb   = (const float*)d_in[1];
  const float* w_ih0 = (const float*)d_in[2];
  const float* w_hh0 = (const float*)d_in[3];
  const float* b_ih0 = (const float*)d_in[4];
  const float* b_hh0 = (const float*)d_in[5];
  const float* w_ih1 = (const float*)d_in[6];
  const float* w_hh1 = (const float*)d_in[7];
  const float* b_ih1 = (const float*)d_in[8];
  const float* b_hh1 = (const float*)d_in[9];
  const float* fc_w  = (const float*)d_in[10];
  const float* fc_b  = (const float*)d_in[11];
  if (ws_size < WS_NEEDED) return;
  unsigned char* ws = (unsigned char*)d_ws;
  hipMemsetAsync(ws + WS_FLAGS, 0, WS_FLAG_B, stream);         // barrier flags (padded)
  hipMemsetAsync(ws + WS_H0, 0, HSLOT_B, stream);              // h0 init slot (zeros)
  hipMemsetAsync(ws + WS_H1, 0, HSLOT_B, stream);              // h1 init slot (zeros)
  hipMemsetAsync(ws + WS_CNT, 0, 4u*NB*NV, stream);            // token histogram
  hipLaunchKernelGGL(lstm_all, dim3(NWG), dim3(NTH), 0, stream,
                     x, emb, w_ih0, w_hh0, b_ih0, b_hh0,
                     w_ih1, w_hh1, b_ih1, b_hh1, fc_w, fc_b,
                     (float*)d_out, (unsigned char*)d_ws);
}

// Round 5
// 998.858 us; speedup vs baseline: 14.1712x; 1.7657x over previous
//
#include <hip/hip_runtime.h>
#include <hip/hip_bf16.h>
#include <stdint.h>

// Problem constants
#define NB 64      // batch
#define NT 128     // seq len
#define NE 512     // embed
#define NH 1024    // hidden
#define NV 32000   // vocab
#define NM (NB*NT) // 8192 flattened (t-major: m = t*64 + b)

// Kernel config
#define NWG 256    // one workgroup per CU, all co-resident
#define NTH 512    // 8 waves
#define FLAG_STRIDE 32u   // one flag per 128-B LLC line (poll-contention fix)

// ws byte offsets. History slots are write-once per launch: slot s of hist0
// holds h0[s-1] (slot 0 = zeros); hist1 slot s holds h1[s-1].
// Slots are FRAGMENT-MAJOR: element (rb,kk,lane,j) at ((rb*32+kk)*64+lane)*8+j
// holds h[rb*16 + (lane&15)][kk*32 + (lane>>4)*8 + j]  -> wave reads are
// contiguous 1 KB per (rb,kk); writes are 8 B per batch row (loop-invariant addr).
#define HSLOT_B (NB*NH*2u)                      // 131072 B per history slot
#define WS_FLAGS   0u
#define WS_FLAG_B  (NWG*FLAG_STRIDE*4u)         // 32768 B
#define WS_H0      WS_FLAG_B
#define WS_H1      (WS_H0 + 129u*HSLOT_B)       // 16941056
#define WS_CNT     (WS_H1 + 129u*HSLOT_B)       // 33849344
#define WS_XS0     (WS_CNT + 4u*NB*NV)          // 42041344
#define WS_NEEDED  (WS_XS0 + 2u*NM*NE)          // 50429952

typedef __attribute__((ext_vector_type(8))) short bf16x8;
typedef __attribute__((ext_vector_type(4))) float f32x4;

__device__ __forceinline__ unsigned short f2bf(float f) {
  unsigned u = __float_as_uint(f);
  u += 0x7FFFu + ((u >> 16) & 1u);   // round-nearest-even
  return (unsigned short)(u >> 16);
}
__device__ __forceinline__ float sigmoidf_(float x) {
  return 1.0f / (1.0f + expf(-x));
}
__device__ __forceinline__ bf16x8 pack8(float4 a, float4 b) {
  bf16x8 v;
  v[0]=(short)f2bf(a.x); v[1]=(short)f2bf(a.y); v[2]=(short)f2bf(a.z); v[3]=(short)f2bf(a.w);
  v[4]=(short)f2bf(b.x); v[5]=(short)f2bf(b.y); v[6]=(short)f2bf(b.z); v[7]=(short)f2bf(b.w);
  return v;
}

// Light grid barrier: no fences, no acquire/release cache maintenance.
// __syncthreads drains vmcnt (sc1 data stores complete at LLC) before the
// flag publish. 256 parallel pollers, one padded flag each, relaxed loads.
__device__ __forceinline__ void gbar_light(unsigned* flags, unsigned n) {
  __syncthreads();
  if (threadIdx.x == 0)
    __hip_atomic_store(&flags[(unsigned)blockIdx.x * FLAG_STRIDE], n,
                       __ATOMIC_RELAXED, __HIP_MEMORY_SCOPE_AGENT);
  if (threadIdx.x < NWG) {
    while (__hip_atomic_load(&flags[(unsigned)threadIdx.x * FLAG_STRIDE],
                             __ATOMIC_RELAXED, __HIP_MEMORY_SCOPE_AGENT) < n)
      __builtin_amdgcn_s_sleep(8);
  }
  __syncthreads();
}

#define MFMA(a,b,c) __builtin_amdgcn_mfma_f32_16x16x32_bf16((a),(b),(c),0,0,0)

__global__ void __launch_bounds__(NTH, 2)
lstm_all(const int* __restrict__ x, const float* __restrict__ emb,
         const float* __restrict__ w_ih0, const float* __restrict__ w_hh0,
         const float* __restrict__ b_ih0, const float* __restrict__ b_hh0,
         const float* __restrict__ w_ih1, const float* __restrict__ w_hh1,
         const float* __restrict__ b_ih1, const float* __restrict__ b_hh1,
         const float* __restrict__ fc_w, const float* __restrict__ fc_b,
         float* __restrict__ out, unsigned char* __restrict__ wsb)
{
  __shared__ unsigned short sWih1[32*64*8];            // 32 KB, fragment order
  __shared__ unsigned short sWih0[16*64*8];            // 16 KB, fragment order
  __shared__ float sG0[NB][16], sG1a[NB][16], sG1b[NB][16], sGih[NB][16];
  __shared__ float sB0[16], sB1[16];
  __shared__ alignas(8) unsigned short sH0[NB][4], sH1[NB][4];

  const int wg  = blockIdx.x;
  const int tid = threadIdx.x;
  const int wave = tid >> 6, lane = tid & 63;
  const int lr = lane & 15, lq = lane >> 4;

  unsigned* flags = (unsigned*)(wsb + WS_FLAGS);
  unsigned short* hist0 = (unsigned short*)(wsb + WS_H0);
  unsigned short* hist1 = (unsigned short*)(wsb + WS_H1);
  unsigned* counts = (unsigned*)(wsb + WS_CNT);
  unsigned short* xs0 = (unsigned short*)(wsb + WS_XS0);

  // gate-row this lane's B-fragments correspond to: gate=(lr>>2), unit=(lr&3)
  const int gr = (lr >> 2)*NH + wg*4 + (lr & 3);

  // publish offset within a fragment-major slot for this wg's 4 units,
  // batch row = lane (loop-invariant)
  const unsigned kkw = (unsigned)wg >> 3, lqw = ((unsigned)wg >> 1) & 3, j0 = ((unsigned)wg & 1)*4;
  const size_t pubOff = ((size_t)((lane>>4)*32 + kkw)*64 + lqw*16 + (lane&15))*8 + j0;

  // ---- phase 1a: step-invariant B-fragments of w_hh0 (waves 0-3) or w_hh1
  // (waves 4-7) into 128 VGPRs.
  bf16x8 breg[32];
  {
    const float* wsrc = (wave < 4 ? w_hh0 : w_hh1) + (size_t)gr*NH + lq*8;
    #pragma unroll
    for (int kk = 0; kk < 32; ++kk)
      breg[kk] = pack8(*(const float4*)(wsrc + kk*32), *(const float4*)(wsrc + kk*32 + 4));
  }

  // ---- phase 1b: gather embeddings -> xs0 (bf16, FRAGMENT-MAJOR over
  // mblk=m>>4), published sc1. element ((mblk*16+kk)*64 + lq*16 + lr)*8+j
  for (int i = wg*NTH + tid; i < NM*(NE/8); i += NWG*NTH) {
    int m = i >> 6;              // NE/8 = 64 vec8 per row
    int e8 = (i & 63) << 3;
    int t = m >> 6, b = m & 63;
    int tok = x[b*NT + t];
    const float* s = emb + (size_t)tok*NE + e8;
    union { bf16x8 v8; unsigned long long u[2]; } u;
    u.v8 = pack8(*(const float4*)s, *(const float4*)(s + 4));
    int mblk = m >> 4, lrm = m & 15;
    int kk = e8 >> 5, lqm = (e8 >> 3) & 3;
    size_t elem = ((size_t)(mblk*16 + kk)*64 + lqm*16 + lrm) * 8;
    unsigned long long* dst = (unsigned long long*)(xs0 + elem);
    __hip_atomic_store(dst,   u.u[0], __ATOMIC_RELAXED, __HIP_MEMORY_SCOPE_AGENT);
    __hip_atomic_store(dst+1, u.u[1], __ATOMIC_RELAXED, __HIP_MEMORY_SCOPE_AGENT);
  }

  // ---- phase 1c: w_ih1 / w_ih0 slices -> LDS in fragment order
  for (int i = tid; i < 32*64; i += NTH) {      // w_ih1: kk<32
    int kk = i >> 6, l = i & 63;
    int glr = l & 15, glq = l >> 4;
    int ggr = (glr >> 2)*NH + wg*4 + (glr & 3);
    const float* p = w_ih1 + (size_t)ggr*NH + kk*32 + glq*8;
    ((bf16x8*)sWih1)[i] = pack8(*(const float4*)p, *(const float4*)(p + 4));
  }
  for (int i = tid; i < 16*64; i += NTH) {      // w_ih0: kk<16 (K=512)
    int kk = i >> 6, l = i & 63;
    int glr = l & 15, glq = l >> 4;
    int ggr = (glr >> 2)*NH + wg*4 + (glr & 3);
    const float* p = w_ih0 + (size_t)ggr*NE + kk*32 + glq*8;
    ((bf16x8*)sWih0)[i] = pack8(*(const float4*)p, *(const float4*)(p + 4));
  }
  if (tid < 16) {
    int g2 = (tid >> 2)*NH + wg*4 + (tid & 3);
    sB0[tid] = b_ih0[g2] + b_hh0[g2];
    sB1[tid] = b_ih1[g2] + b_hh1[g2];
  }
  // ---- phase 1d: token histogram (counts zeroed by host memset)
  {
    int i = wg*NTH + tid;
    if (i < NB*NT) {
      int b = i >> 7;
      atomicAdd(&counts[(size_t)b*NV + x[i]], 1u);
    }
  }
  unsigned bar = 1;
  gbar_light(flags, bar);

  // ---- phase 3: pipelined 2-layer scan, 129 grid steps ----
  // step t: waves 0-3: a0 = h0[t-1]@w_hh0^T (regs), a1 = h0[t-1]@w_ih1^T (LDS)
  //         waves 4-7: a2 = h1[t-2]@w_hh1^T (regs), aih = xs0[t]@w_ih0^T (LDS)
  // cells tid<256: layer0 time t (a0+aih+b0);  tid>=256: layer1 time t-1 (a1+a2+b1)
  float c_reg = 0.f;
  const int cb = (tid & 255) >> 2, cu = tid & 3;
  for (int t = 0; t <= NT; ++t) {
    if (wave < 4) {
      // contiguous 1 KB per (wave,kk): coalesced fragment loads
      const unsigned short* A = hist0 + (size_t)t*(NB*NH) + (size_t)(wave*2048 + lane)*8;
      f32x4 a0 = {0.f,0.f,0.f,0.f}, a1 = {0.f,0.f,0.f,0.f};
      #pragma unroll
      for (int kk = 0; kk < 32; ++kk) {
        bf16x8 af = *(const bf16x8*)(A + kk*512);
        a0 = MFMA(af, breg[kk], a0);
        a1 = MFMA(af, ((const bf16x8*)sWih1)[kk*64 + lane], a1);
      }
      #pragma unroll
      for (int r = 0; r < 4; ++r) {
        sG0 [wave*16 + lq*4 + r][lr] = a0[r];
        sG1a[wave*16 + lq*4 + r][lr] = a1[r];
      }
    } else {
      if (t >= 1) {
        const unsigned short* A = hist1 + (size_t)(t-1)*(NB*NH) + (size_t)((wave-4)*2048 + lane)*8;
        f32x4 a2 = {0.f,0.f,0.f,0.f};
        #pragma unroll
        for (int kk = 0; kk < 32; ++kk)
          a2 = MFMA(*(const bf16x8*)(A + kk*512), breg[kk], a2);
        #pragma unroll
        for (int r = 0; r < 4; ++r) sG1b[(wave-4)*16 + lq*4 + r][lr] = a2[r];
      }
      if (t < NT) {
        const unsigned short* A = xs0 + ((size_t)(t*4 + (wave-4))*1024 + lane)*8;
        f32x4 ai = {0.f,0.f,0.f,0.f};
        #pragma unroll
        for (int kk = 0; kk < 16; ++kk)
          ai = MFMA(*(const bf16x8*)(A + kk*512), ((const bf16x8*)sWih0)[kk*64 + lane], ai);
        #pragma unroll
        for (int r = 0; r < 4; ++r) sGih[(wave-4)*16 + lq*4 + r][lr] = ai[r];
      }
    }
    __syncthreads();
    if (tid < 256) {
      if (t < NT) {
        float gi = sG0[cb][cu]    + sGih[cb][cu]    + sB0[cu];
        float gf = sG0[cb][4+cu]  + sGih[cb][4+cu]  + sB0[4+cu];
        float gg = sG0[cb][8+cu]  + sGih[cb][8+cu]  + sB0[8+cu];
        float go = sG0[cb][12+cu] + sGih[cb][12+cu] + sB0[12+cu];
        float ii = sigmoidf_(gi), ff = sigmoidf_(gf), g = tanhf(gg), oo = sigmoidf_(go);
        c_reg = ff*c_reg + ii*g;
        sH0[cb][cu] = f2bf(oo * tanhf(c_reg));
      }
    } else {
      if (t >= 1) {
        float gi = sG1a[cb][cu]    + sG1b[cb][cu]    + sB1[cu];
        float gf = sG1a[cb][4+cu]  + sG1b[cb][4+cu]  + sB1[4+cu];
        float gg = sG1a[cb][8+cu]  + sG1b[cb][8+cu]  + sB1[8+cu];
        float go = sG1a[cb][12+cu] + sG1b[cb][12+cu] + sB1[12+cu];
        float ii = sigmoidf_(gi), ff = sigmoidf_(gf), g = tanhf(gg), oo = sigmoidf_(go);
        c_reg = ff*c_reg + ii*g;
        sH1[cb][cu] = f2bf(oo * tanhf(c_reg));
      }
    }
    __syncthreads();
    // publish h slices: 8 B per batch row (=lane) at fragment-major pubOff
    if (wave == 0 && t < NT) {
      unsigned long long v = *(const unsigned long long*)&sH0[lane][0];
      __hip_atomic_store((unsigned long long*)(hist0 + (size_t)(t+1)*(NB*NH) + pubOff),
                         v, __ATOMIC_RELAXED, __HIP_MEMORY_SCOPE_AGENT);
    }
    if (wave == 1 && t >= 1) {
      unsigned long long v = *(const unsigned long long*)&sH1[lane][0];
      __hip_atomic_store((unsigned long long*)(hist1 + (size_t)t*(NB*NH) + pubOff),
                         v, __ATOMIC_RELAXED, __HIP_MEMORY_SCOPE_AGENT);
    }
    gbar_light(flags, ++bar);
  }

  // ---- phase 4: FC + repetition penalty (h1[127] = hist1 slot 128, fragment-major) ----
  {
    const unsigned short* ab = hist1 + (size_t)128*(NB*NH) + (size_t)lane*8;
    int tile = wg*8 + wave;                    // 2048 waves, 2000 col-tiles of 16
    if (tile < NV/16) {
      int c0 = tile*16;
      const float* wb = fc_w + (size_t)(c0 + lr)*NH + lq*8;
      f32x4 acc[4] = {{0.f,0.f,0.f,0.f},{0.f,0.f,0.f,0.f},{0.f,0.f,0.f,0.f},{0.f,0.f,0.f,0.f}};
      #pragma unroll 4
      for (int kk = 0; kk < 32; ++kk) {
        bf16x8 bfv = pack8(*(const float4*)(wb + kk*32), *(const float4*)(wb + kk*32 + 4));
        #pragma unroll
        for (int mt = 0; mt < 4; ++mt) {
          bf16x8 af = *(const bf16x8*)(ab + (size_t)(mt*32 + kk)*512);
          acc[mt] = MFMA(af, bfv, acc[mt]);
        }
      }
      int c = c0 + lr;
      float fb = fc_b[c];
      #pragma unroll
      for (int mt = 0; mt < 4; ++mt) {
        #pragma unroll
        for (int r = 0; r < 4; ++r) {
          int b = mt*16 + lq*4 + r;
          unsigned cnt = counts[(size_t)b*NV + c];
          float v = (acc[mt][r] + fb) * exp2f(-0.26303440583379378f * (float)cnt);
          out[(size_t)b*NV + c] = v;
        }
      }
    }
  }
}

extern "C" void kernel_launch(void* const* d_in, const int* in_sizes, int n_in,
                              void* d_out, int out_size, void* d_ws, size_t ws_size,
                              hipStream_t stream) {
  const int*   x     = (const int*)  d_in[0];
  const float* emb   = (const float*)d_in[1];
  const float* w_ih0 = (const float*)d_in[2];
  const float* w_hh0 = (const float*)d_in[3];
  const float* b_ih0 = (const float*)d_in[4];
  const float* b_hh0 = (const float*)d_in[5];
  const float* w_ih1 = (const float*)d_in[6];
  const float* w_hh1 = (const float*)d_in[7];
  const float* b_ih1 = (const float*)d_in[8];
  const float* b_hh1 = (const float*)d_in[9];
  const float* fc_w  = (const float*)d_in[10];
  const float* fc_b  = (const float*)d_in[11];
  if (ws_size < WS_NEEDED) return;
  unsigned char* ws = (unsigned char*)d_ws;
  hipMemsetAsync(ws + WS_FLAGS, 0, WS_FLAG_B, stream);         // barrier flags (padded)
  hipMemsetAsync(ws + WS_H0, 0, HSLOT_B, stream);              // h0 init slot (zeros)
  hipMemsetAsync(ws + WS_H1, 0, HSLOT_B, stream);              // h1 init slot (zeros)
  hipMemsetAsync(ws + WS_CNT, 0, 4u*NB*NV, stream);            // token histogram
  hipLaunchKernelGGL(lstm_all, dim3(NWG), dim3(NTH), 0, stream,
                     x, emb, w_ih0, w_hh0, b_ih0, b_hh0,
                     w_ih1, w_hh1, b_ih1, b_hh1, fc_w, fc_b,
                     (float*)d_out, (unsigned char*)d_ws);
}